// Round 2
// baseline (98.157 us; speedup 1.0000x reference)
//
#include <hip/hip_runtime.h>

#define NB 64
#define NT 128
#define ND 128
#define NE 512
#define EPSV 1e-5f
#define XA_STR 136   // shorts; 272B rows: 16B-aligned

typedef __bf16 bf16x8 __attribute__((ext_vector_type(8)));
typedef float f32x4 __attribute__((ext_vector_type(4)));

union Frag { unsigned short u[8]; bf16x8 v; };

__device__ __forceinline__ unsigned short f2bf(float f) {
  unsigned u = __float_as_uint(f);
  u += 0x7FFFu + ((u >> 16) & 1u);   // RNE
  return (unsigned short)(u >> 16);
}
__device__ __forceinline__ float bf2f(unsigned short h) {
  return __uint_as_float(((unsigned)h) << 16);
}

#define LGKM0() asm volatile("s_waitcnt lgkmcnt(0)" ::: "memory")
#define VMCNT0() asm volatile("s_waitcnt vmcnt(0)" ::: "memory")

// Block = (slot s, E-quarter q). 256 threads = 4 waves; wave w owns 32 cols.
// 12 pipeline stages: S0..S7 = {Wu,Wg} x kk(4 K-slices of 32), S8..S11 = Wd
// x kk. Each stage = 32 rows x 128 cols fp32 = 16KB, double-buffered,
// streamed via global_load_lds with chunk-XOR swizzle (linear LDS dest,
// pre-swizzled global source; same XOR applied on the LDS read side).
__global__ __launch_bounds__(256) void mlp_main(
    const float* __restrict__ Xsrc, const float* __restrict__ Wu,
    const float* __restrict__ bu, const float* __restrict__ Wg,
    const float* __restrict__ bg, const float* __restrict__ Wd,
    unsigned short* __restrict__ partial)
{
  const int bid = blockIdx.x;
  const int s = bid >> 2, q = bid & 3;
  const int tid = threadIdx.x;
  const int wv = tid >> 6, lane = tid & 63;
  const int l16 = lane & 15, lg = lane >> 4;

  __shared__ __align__(16) float wb[2][4096];            // 2 x 16KB stage buffers
  __shared__ __align__(16) unsigned short xa[NB * XA_STR]; // Xs (up), then A2 (down)

  const float* WuS = Wu + (size_t)s * ND * NE + q * 128;
  const float* WgS = Wg + (size_t)s * ND * NE + q * 128;
  const float* WdS = Wd + (size_t)s * NE * ND + (size_t)q * 128 * ND;

  auto ISSUE = [&](int st) {
    const float* base; int rs;
    if (st < 8) { int kk = st >> 1; base = ((st & 1) ? WgS : WuS) + kk * 32 * NE; rs = NE; }
    else        { int kk = st - 8;  base = WdS + kk * 32 * ND;                    rs = ND; }
    float* buf = wb[st & 1];
#pragma unroll
    for (int r = 0; r < 4; ++r) {
      const int pb = r * 256 + wv * 64;     // wave-uniform chunk base
      const int p  = pb + lane;
      const int k  = p >> 5;
      const int cg = (p & 31) ^ ((k >> 3) << 1);   // source pre-swizzle
      const float* src = base + k * rs + cg * 4;
      __builtin_amdgcn_global_load_lds(
          (const __attribute__((address_space(1))) void*)src,
          (__attribute__((address_space(3))) void*)(buf + pb * 4),
          16, 0, 0);
    }
  };

  // B-fragment: element (k=lg*8+j, c) lives at dword k*128 + ((c>>2)^(lg<<1))*4 + (c&3)
  auto BFRAG = [&](const float* buf, int c) -> Frag {
    Frag f;
    const float* bp = buf + lg * 1024 + ((((c >> 2) ^ (lg << 1)) << 2) | (c & 3));
#pragma unroll
    for (int j = 0; j < 8; ++j) f.u[j] = f2bf(bp[j * 128]);
    return f;
  };

  // bias preload (keeps the main loop free of stray vmem ops)
  const int c0 = wv * 32 + l16, c1 = c0 + 16;
  const float bu0 = bu[s * NE + q * 128 + c0], bu1 = bu[s * NE + q * 128 + c1];
  const float bg0 = bg[s * NE + q * 128 + c0], bg1 = bg[s * NE + q * 128 + c1];

  ISSUE(0);
  // stage X[b][d] = Xsrc[b, d, s] (transposed gather, L2-resident)
  for (int i = tid; i < NB * ND; i += 256) {
    const int b = i >> 7, d = i & 127;
    xa[b * XA_STR + d] = f2bf(Xsrc[(b << 14) + (d << 7) + s]);
  }
  LGKM0(); VMCNT0();
  __builtin_amdgcn_s_barrier();

  Frag a[4];
  f32x4 au[2][4] = {}, ag[2][4] = {}, ad[2][4] = {};

  for (int st = 0; st < 12; ++st) {
    if (st < 11) ISSUE(st + 1);
    const float* buf = wb[st & 1];
    if (st < 8) {
      const int kk = st >> 1;
      if (!(st & 1)) {                       // Wu slice: refresh A-frags
#pragma unroll
        for (int mt = 0; mt < 4; ++mt)
          a[mt].v = *(const bf16x8*)&xa[(mt * 16 + l16) * XA_STR + kk * 32 + lg * 8];
#pragma unroll
        for (int n16 = 0; n16 < 2; ++n16) {
          Frag f = BFRAG(buf, wv * 32 + n16 * 16 + l16);
#pragma unroll
          for (int mt = 0; mt < 4; ++mt)
            au[n16][mt] = __builtin_amdgcn_mfma_f32_16x16x32_bf16(a[mt].v, f.v, au[n16][mt], 0, 0, 0);
        }
      } else {                               // Wg slice (same kk, same A-frags)
#pragma unroll
        for (int n16 = 0; n16 < 2; ++n16) {
          Frag f = BFRAG(buf, wv * 32 + n16 * 16 + l16);
#pragma unroll
          for (int mt = 0; mt < 4; ++mt)
            ag[n16][mt] = __builtin_amdgcn_mfma_f32_16x16x32_bf16(a[mt].v, f.v, ag[n16][mt], 0, 0, 0);
        }
        if (st == 7) {
          // A2 epilogue: up*silu(gate) -> xa (overwrites Xs; last Xs read was st=6)
#pragma unroll
          for (int n16 = 0; n16 < 2; ++n16) {
            const int col = wv * 32 + n16 * 16 + l16;
            const float buv = n16 ? bu1 : bu0, bgv = n16 ? bg1 : bg0;
#pragma unroll
            for (int mt = 0; mt < 4; ++mt)
#pragma unroll
              for (int r = 0; r < 4; ++r) {
                const int m = mt * 16 + lg * 4 + r;
                const float uv = au[n16][mt][r] + buv;
                const float gv = ag[n16][mt][r] + bgv;
                xa[m * XA_STR + col] = f2bf(uv * (gv / (1.f + __expf(-gv))));
              }
          }
        }
      }
    } else {                                 // down: K = this block's 128 e-cols
      const int kk = st - 8;
#pragma unroll
      for (int mt = 0; mt < 4; ++mt)
        a[mt].v = *(const bf16x8*)&xa[(mt * 16 + l16) * XA_STR + kk * 32 + lg * 8];
#pragma unroll
      for (int n16 = 0; n16 < 2; ++n16) {
        Frag f = BFRAG(buf, wv * 32 + n16 * 16 + l16);
#pragma unroll
        for (int mt = 0; mt < 4; ++mt)
          ad[n16][mt] = __builtin_amdgcn_mfma_f32_16x16x32_bf16(a[mt].v, f.v, ad[n16][mt], 0, 0, 0);
      }
    }
    LGKM0(); VMCNT0();
    __builtin_amdgcn_s_barrier();
  }

  unsigned short* po = partial + (size_t)bid * (NB * ND);
#pragma unroll
  for (int n16 = 0; n16 < 2; ++n16) {
    const int dcol = wv * 32 + n16 * 16 + l16;
#pragma unroll
    for (int mt = 0; mt < 4; ++mt)
#pragma unroll
      for (int r = 0; r < 4; ++r)
        po[(mt * 16 + lg * 4 + r) * ND + dcol] = f2bf(ad[n16][mt][r]);
  }
}

// Reduce 4 bf16 partials + bias + residual, RMSNorm, store y[b,s,d].
__global__ __launch_bounds__(256) void finish(
    const unsigned short* __restrict__ partial, const float* __restrict__ Xsrc,
    const float* __restrict__ bd, const float* __restrict__ scale,
    float* __restrict__ y)
{
  const int s = blockIdx.x >> 1, half = blockIdx.x & 1;
  const int wv = threadIdx.x >> 6, lane = threadIdx.x & 63;
  const int d0 = 2 * lane, d1 = d0 + 1;
  const float sc0 = scale[d0], sc1 = scale[d1];
  const float bd0 = bd[s * ND + d0], bd1 = bd[s * ND + d1];
  const unsigned short* pbase = partial + (size_t)(s * 4) * (NB * ND);
  for (int i = 0; i < 8; ++i) {
    const int b = half * 32 + i * 4 + wv;
    float z0 = bd0 + Xsrc[(b << 14) + (d0 << 7) + s];
    float z1 = bd1 + Xsrc[(b << 14) + (d1 << 7) + s];
#pragma unroll
    for (int pp = 0; pp < 4; ++pp) {
      const unsigned short* pr = pbase + pp * (NB * ND) + b * ND + d0;
      z0 += bf2f(pr[0]); z1 += bf2f(pr[1]);
    }
    float ss = z0 * z0 + z1 * z1;
#pragma unroll
    for (int off = 32; off; off >>= 1) ss += __shfl_xor(ss, off);
    const float inv = rsqrtf(ss * (1.f / 128.f) + EPSV);
    y[((b << 7) + s) * 128 + d0] = z0 * inv * sc0;
    y[((b << 7) + s) * 128 + d1] = z1 * inv * sc1;
  }
}

extern "C" void kernel_launch(void* const* d_in, const int* in_sizes, int n_in,
                              void* d_out, int out_size, void* d_ws, size_t ws_size,
                              hipStream_t stream) {
  (void)in_sizes; (void)n_in; (void)out_size; (void)ws_size;
  const float* x   = (const float*)d_in[0];
  const float* W1u = (const float*)d_in[1];
  const float* b1u = (const float*)d_in[2];
  const float* W1g = (const float*)d_in[3];
  const float* b1g = (const float*)d_in[4];
  const float* W1d = (const float*)d_in[5];
  const float* b1d = (const float*)d_in[6];
  const float* sc1 = (const float*)d_in[7];
  const float* W2u = (const float*)d_in[8];
  const float* b2u = (const float*)d_in[9];
  const float* W2g = (const float*)d_in[10];
  const float* b2g = (const float*)d_in[11];
  const float* W2d = (const float*)d_in[12];
  const float* b2d = (const float*)d_in[13];
  const float* sc2 = (const float*)d_in[14];
  float* out = (float*)d_out;

  float* x1s = (float*)d_ws;                                  // [B][128][128] f32, 4.19 MB
  unsigned short* part = (unsigned short*)(x1s + (size_t)NB * NT * ND); // [512][64][128] bf16, 8.39 MB

  mlp_main<<<512, 256, 0, stream>>>(x,   W1u, b1u, W1g, b1g, W1d, part);
  finish  <<<256, 256, 0, stream>>>(part, x,   b1d, sc1, x1s);
  mlp_main<<<512, 256, 0, stream>>>(x1s, W2u, b2u, W2g, b2g, W2d, part);
  finish  <<<256, 256, 0, stream>>>(part, x1s, b2d, sc2, out);
}

// Round 3
// 60.646 us; speedup vs baseline: 1.6185x; 1.6185x over previous
//
#include <hip/hip_runtime.h>

typedef __bf16 bf16x8 __attribute__((ext_vector_type(8)));
typedef float f32x4 __attribute__((ext_vector_type(4)));
typedef unsigned int uint;

union Frag { __bf16 b[8]; bf16x8 v; unsigned short u[8]; };

__device__ __forceinline__ unsigned short bfbits(float f) {
  union { __bf16 h; unsigned short s; } c; c.h = (__bf16)f; return c.s;
}
__device__ __forceinline__ float bf2f(unsigned short h) {
  return __uint_as_float(((uint)h) << 16);
}

// barrier WITHOUT vmcnt drain: keeps global prefetch in flight
#define BAR() asm volatile("s_waitcnt lgkmcnt(0)\n\ts_barrier" ::: "memory")

// dst[s][b][f] (bf16) = src[b][f][s]   (B=64, F=128, S=128)
template <typename T>
__global__ __launch_bounds__(256) void transpose_in(const T* __restrict__ src,
                                                    unsigned short* __restrict__ dst) {
  __shared__ unsigned short tile[64][68];
  const int b  = blockIdx.x >> 2;
  const int f0 = ((blockIdx.x >> 1) & 1) * 64;
  const int s0 = (blockIdx.x & 1) * 64;
  const int j = threadIdx.x & 63, i0 = threadIdx.x >> 6;
  const T* sp = src + b * 16384 + f0 * 128 + s0 + j;
#pragma unroll
  for (int p = 0; p < 16; ++p) {
    const int i = i0 + p * 4;
    if constexpr (sizeof(T) == 4) tile[i][j] = bfbits((float)sp[i * 128]);
    else                          tile[i][j] = (unsigned short)sp[i * 128];
  }
  __syncthreads();
  unsigned short* dp = dst + s0 * 8192 + b * 128 + f0 + j;
#pragma unroll
  for (int p = 0; p < 16; ++p) {
    const int i = i0 + p * 4;
    dp[(size_t)i * 8192] = tile[j][i];
  }
}

// Block = (slot s, E-quarter q): 512 threads = 8 waves, wave owns 16 cols.
// Weights stream HBM->registers (double-buffered, no LDS, no vmcnt drains).
__global__ __launch_bounds__(512, 4) void mlp_main(
    const unsigned short* __restrict__ Xt,   // [128][64][128] bf16
    const float* __restrict__ Wu, const float* __restrict__ bu,
    const float* __restrict__ Wg, const float* __restrict__ bg,
    const float* __restrict__ Wd,
    unsigned short* __restrict__ partial)    // [512][64][128] bf16
{
  const int bid = blockIdx.x;
  const int s = bid >> 2, q = bid & 3;
  const int tid = threadIdx.x;
  const int wv = tid >> 6, lane = tid & 63;
  const int l16 = lane & 15, lg = lane >> 4;
  const int col = wv * 16 + l16;             // this lane's weight column (local)

  __shared__ __align__(16) unsigned short xa[64 * 136];  // X then A2, swizzled

  const float* WuS = Wu + (size_t)s * 65536 + q * 128;
  const float* WgS = Wg + (size_t)s * 65536 + q * 128;
  const float* WdS = Wd + (size_t)s * 65536 + (size_t)q * 16384;

  const float* pu = WuS + (size_t)(lg * 8) * 512 + col;
  const float* pg = WgS + (size_t)(lg * 8) * 512 + col;
  const float* pd = WdS + (size_t)(lg * 8) * 128 + col;

  // ---- prologue: issue first weight slice, then stage X ----
  float ub[2][8], gb[2][8], db[2][8];
#pragma unroll
  for (int j = 0; j < 8; ++j) { ub[0][j] = pu[(size_t)j * 512]; gb[0][j] = pg[(size_t)j * 512]; }
  const float buv = bu[s * 512 + q * 128 + col];
  const float bgv = bg[s * 512 + q * 128 + col];

#pragma unroll
  for (int cc = 0; cc < 2; ++cc) {
    const int c = tid * 2 + cc;              // 1024 16B-chunks
    const int m = c >> 4, ch = c & 15;
    uint4 v = *(const uint4*)(Xt + (size_t)s * 8192 + m * 128 + ch * 8);
    *(uint4*)&xa[m * 136 + ((ch ^ (m & 7)) << 3)] = v;
  }
  BAR();

  // ---- up/gate: K=128, double-buffered weight registers ----
  Frag a[4];
  f32x4 au[4] = {}, ag[4] = {};
#pragma unroll
  for (int kk = 0; kk < 4; ++kk) {
    if (kk < 3) {
#pragma unroll
      for (int j = 0; j < 8; ++j) {
        ub[(kk + 1) & 1][j] = pu[(size_t)((kk + 1) * 32 + j) * 512];
        gb[(kk + 1) & 1][j] = pg[(size_t)((kk + 1) * 32 + j) * 512];
      }
    }
#pragma unroll
    for (int mt = 0; mt < 4; ++mt) {
      const int m = mt * 16 + l16;
      a[mt].v = *(const bf16x8*)&xa[m * 136 + (((kk * 4 + lg) ^ (m & 7)) << 3)];
    }
    Frag fu, fg;
#pragma unroll
    for (int j = 0; j < 8; ++j) {
      fu.b[j] = (__bf16)ub[kk & 1][j];
      fg.b[j] = (__bf16)gb[kk & 1][j];
    }
#pragma unroll
    for (int mt = 0; mt < 4; ++mt) {
      au[mt] = __builtin_amdgcn_mfma_f32_16x16x32_bf16(a[mt].v, fu.v, au[mt], 0, 0, 0);
      ag[mt] = __builtin_amdgcn_mfma_f32_16x16x32_bf16(a[mt].v, fg.v, ag[mt], 0, 0, 0);
    }
  }

  // issue first down-weight slice so it flies during the epilogue
#pragma unroll
  for (int j = 0; j < 8; ++j) db[0][j] = pd[(size_t)j * 128];

  // silu epilogue (VALU, overlaps db[0] load)
  float a2v[4][4];
#pragma unroll
  for (int mt = 0; mt < 4; ++mt)
#pragma unroll
    for (int r = 0; r < 4; ++r) {
      const float uv = au[mt][r] + buv;
      const float gv = ag[mt][r] + bgv;
      a2v[mt][r] = uv * (gv / (1.f + __expf(-gv)));
    }

  BAR();  // all waves done reading X from xa
#pragma unroll
  for (int mt = 0; mt < 4; ++mt)
#pragma unroll
    for (int r = 0; r < 4; ++r) {
      const int m = mt * 16 + lg * 4 + r;
      xa[m * 136 + (((col >> 3) ^ (m & 7)) << 3) + (col & 7)] = bfbits(a2v[mt][r]);
    }
  BAR();  // A2 visible to all

  // ---- down: K=128 (this quarter's e-cols) ----
  f32x4 ad[4] = {};
#pragma unroll
  for (int kk = 0; kk < 4; ++kk) {
    if (kk < 3) {
#pragma unroll
      for (int j = 0; j < 8; ++j)
        db[(kk + 1) & 1][j] = pd[(size_t)((kk + 1) * 32 + j) * 128];
    }
#pragma unroll
    for (int mt = 0; mt < 4; ++mt) {
      const int m = mt * 16 + l16;
      a[mt].v = *(const bf16x8*)&xa[m * 136 + (((kk * 4 + lg) ^ (m & 7)) << 3)];
    }
    Frag fd;
#pragma unroll
    for (int j = 0; j < 8; ++j) fd.b[j] = (__bf16)db[kk & 1][j];
#pragma unroll
    for (int mt = 0; mt < 4; ++mt)
      ad[mt] = __builtin_amdgcn_mfma_f32_16x16x32_bf16(a[mt].v, fd.v, ad[mt], 0, 0, 0);
  }

  unsigned short* po = partial + (size_t)bid * 8192;
#pragma unroll
  for (int mt = 0; mt < 4; ++mt)
#pragma unroll
    for (int r = 0; r < 4; ++r)
      po[(mt * 16 + lg * 4 + r) * 128 + col] = bfbits(ad[mt][r]);
}

// sum 4 partials + bias + residual(xt), RMSNorm, store y[b][s][*]
template <typename TO>
__global__ __launch_bounds__(256) void finish(
    const unsigned short* __restrict__ part, const unsigned short* __restrict__ xt,
    const float* __restrict__ bd, const float* __restrict__ scale,
    TO* __restrict__ y)
{
  const int s = blockIdx.x >> 1, half = blockIdx.x & 1;
  const int wvt = threadIdx.x >> 6, lane = threadIdx.x & 63;
  const int d0 = lane * 2;
  const float sc0 = scale[d0], sc1 = scale[d0 + 1];
  const float b0 = bd[s * 128 + d0], b1 = bd[s * 128 + d0 + 1];
  const unsigned short* pb = part + (size_t)s * 4 * 8192;
  const unsigned short* xb = xt + (size_t)s * 8192;
  for (int i = 0; i < 8; ++i) {
    const int b = half * 32 + i * 4 + wvt;
    const uint rx = *(const uint*)(xb + b * 128 + d0);
    float z0 = b0 + bf2f((unsigned short)rx);
    float z1 = b1 + bf2f((unsigned short)(rx >> 16));
#pragma unroll
    for (int p = 0; p < 4; ++p) {
      const uint rp = *(const uint*)(pb + p * 8192 + b * 128 + d0);
      z0 += bf2f((unsigned short)rp);
      z1 += bf2f((unsigned short)(rp >> 16));
    }
    float ss = z0 * z0 + z1 * z1;
#pragma unroll
    for (int off = 32; off; off >>= 1) ss += __shfl_xor(ss, off);
    const float inv = rsqrtf(ss * (1.f / 128.f) + 1e-5f);
    if constexpr (sizeof(TO) == 4) {
      float2 o = make_float2(z0 * inv * sc0, z1 * inv * sc1);
      *(float2*)((float*)y + (size_t)b * 16384 + s * 128 + d0) = o;
    } else {
      const uint o = (uint)bfbits(z0 * inv * sc0) | ((uint)bfbits(z1 * inv * sc1) << 16);
      *(uint*)((unsigned short*)y + (size_t)b * 16384 + s * 128 + d0) = o;
    }
  }
}

extern "C" void kernel_launch(void* const* d_in, const int* in_sizes, int n_in,
                              void* d_out, int out_size, void* d_ws, size_t ws_size,
                              hipStream_t stream) {
  (void)in_sizes; (void)n_in; (void)out_size; (void)ws_size;
  const float* x   = (const float*)d_in[0];
  const float* W1u = (const float*)d_in[1];
  const float* b1u = (const float*)d_in[2];
  const float* W1g = (const float*)d_in[3];
  const float* b1g = (const float*)d_in[4];
  const float* W1d = (const float*)d_in[5];
  const float* b1d = (const float*)d_in[6];
  const float* sc1 = (const float*)d_in[7];
  const float* W2u = (const float*)d_in[8];
  const float* b2u = (const float*)d_in[9];
  const float* W2g = (const float*)d_in[10];
  const float* b2g = (const float*)d_in[11];
  const float* W2d = (const float*)d_in[12];
  const float* b2d = (const float*)d_in[13];
  const float* sc2 = (const float*)d_in[14];
  float* out = (float*)d_out;

  unsigned short* xt   = (unsigned short*)d_ws;          // 2 MB  [s][b][f] bf16
  unsigned short* y1   = xt + (size_t)1048576;           // 2 MB  [b][s][f] bf16
  unsigned short* part = y1 + (size_t)1048576;           // 8 MB  [512][64][128] bf16

  transpose_in<float><<<256, 256, 0, stream>>>(x, xt);
  mlp_main<<<512, 512, 0, stream>>>(xt, W1u, b1u, W1g, b1g, W1d, part);
  finish<unsigned short><<<256, 256, 0, stream>>>(part, xt, b1d, sc1, y1);
  transpose_in<unsigned short><<<256, 256, 0, stream>>>(y1, xt);
  mlp_main<<<512, 512, 0, stream>>>(xt, W2u, b2u, W2g, b2g, W2d, part);
  finish<float><<<256, 256, 0, stream>>>(part, xt, b2d, sc2, out);
}